// Round 7
// baseline (722.147 us; speedup 1.0000x reference)
//
#include <hip/hip_runtime.h>
#include <math.h>

typedef __bf16 bf16;
typedef __bf16 bf16x8 __attribute__((ext_vector_type(8)));
typedef float f32x4 __attribute__((ext_vector_type(4)));

constexpr int cT = 2048;
constexpr int cD = 4096;
constexpr int cH = 32;
constexpr int cKV = 8;
constexpr int cHD = 128;
constexpr float SCALE = 0.08838834764831845f; // 1/sqrt(128)

// Async global->LDS, 16B per lane. LDS dest must be WAVE-UNIFORM base;
// lane i's data lands at base + i*16 (guide §5 caveat).
__device__ __forceinline__ void gl_lds16(const bf16* g, bf16* l) {
  __builtin_amdgcn_global_load_lds(
      (const __attribute__((address_space(1))) unsigned*)g,
      (__attribute__((address_space(3))) unsigned*)l, 16, 0, 0);
}

__device__ inline bf16x8 load8_cvt(const float* __restrict__ p) {
  float4 a = *(const float4*)p;
  float4 b = *(const float4*)(p + 4);
  bf16x8 r;
  r[0] = (bf16)a.x; r[1] = (bf16)a.y; r[2] = (bf16)a.z; r[3] = (bf16)a.w;
  r[4] = (bf16)b.x; r[5] = (bf16)b.y; r[6] = (bf16)b.z; r[7] = (bf16)b.w;
  return r;
}

// ---------------------------------------------------------------------------
// fp32 -> bf16 elementwise (8 elems/thread)
// ---------------------------------------------------------------------------
__global__ __launch_bounds__(256) void convert_kernel(const float* __restrict__ s,
                                                      bf16* __restrict__ d) {
  const size_t i = (size_t)(blockIdx.x * 256 + threadIdx.x) * 8;
  *(bf16x8*)(d + i) = load8_cvt(s + i);
}

// ---------------------------------------------------------------------------
// Transpose + convert: dst[c][r] = (bf16)src[r][c]. src is R x C fp32,
// dst is C x R bf16 (row stride R). 64x64 LDS tile.
// ---------------------------------------------------------------------------
__global__ __launch_bounds__(256) void convT_kernel(const float* __restrict__ src,
                                                    bf16* __restrict__ dst,
                                                    int R, int C) {
  __shared__ float t[64][65];
  const int r0 = blockIdx.y * 64, c0 = blockIdx.x * 64;
  const int tid = threadIdx.x;
  {
    const int lr = tid >> 4, lc = (tid & 15) * 4;
#pragma unroll
    for (int i = 0; i < 4; ++i) {
      float4 v4 = *(const float4*)(src + (size_t)(r0 + lr + i * 16) * C + c0 + lc);
      t[lr + i * 16][lc] = v4.x;
      t[lr + i * 16][lc + 1] = v4.y;
      t[lr + i * 16][lc + 2] = v4.z;
      t[lr + i * 16][lc + 3] = v4.w;
    }
  }
  __syncthreads();
  {
    const int c = tid >> 2, rb = (tid & 3) * 16;
#pragma unroll
    for (int half = 0; half < 2; ++half) {
      bf16x8 o;
#pragma unroll
      for (int j = 0; j < 8; ++j) o[j] = (bf16)t[rb + half * 8 + j][c];
      *(bf16x8*)(dst + (size_t)(c0 + c) * R + r0 + rb + half * 8) = o;
    }
  }
}

// ---------------------------------------------------------------------------
// A-direct GEMM: C[M,N] = A[M,K] * BT[N,K]^T, both bf16 K-major.
// 128xBN tile, BK=32, 256 threads (4 waves, 2x2), wave owns 64 x BN/2.
//
// R5 post-mortem: the LDS READ pipe was the binding resource (per CU per
// slice: 96 KB ds_read + 32 KB gl_lds vs ~85-128 B/cyc => 1000-1500 cyc,
// MFMA only ~620 cyc; occupancy-doubling gave +3% only). Fix: A-fragments
// are wave-private rows of K-major A -> load them DIRECTLY from global
// (16 rows x 64 B = 16 coalesced cache lines per instr, L2-resident panel),
// register-prefetched one slice ahead (T14). Only B goes through LDS
// (R2-proven gl_lds dbuf, single barrier per slice). New LDS budget:
// 48 KB/CU/slice < MFMA 620 cyc -> MFMA-bound.
// ---------------------------------------------------------------------------
template <int BN, typename OutT>
__global__ __launch_bounds__(256) void gemm_bt_kernel(const bf16* __restrict__ A,
                                                      const bf16* __restrict__ BT,
                                                      OutT* __restrict__ C,
                                                      int M, int N, int K) {
  __shared__ __align__(16) bf16 Bs[2][BN][32];
  constexpr int TN = BN / 32;  // n-tiles per wave

  const int tid = threadIdx.x;
  const int lane = tid & 63, w = tid >> 6;
  const int ln = lane & 15, kg = lane >> 4;
  const int m0 = blockIdx.y * 128, n0 = blockIdx.x * BN;
  const int wm = (w >> 1) * 64;
  const int wn = (w & 1) * (BN / 2);

  f32x4 acc[4][TN] = {};

  const int srow = lane >> 2;          // 0..15 within a 16-row chunk
  const int schk = (lane & 3) * 8;     // k-chunk (bf16 elems)
  const bf16* bG = BT + (size_t)(n0 + srow) * K + schk;

  // A-direct row pointers: lane's fragment rows (wave-private).
  const bf16* aR[4];
#pragma unroll
  for (int tm = 0; tm < 4; ++tm)
    aR[tm] = A + (size_t)(m0 + wm + tm * 16 + ln) * K + kg * 8;

  auto stageB = [&](int kt, int db) {
#pragma unroll
    for (int j = 0; j < BN / 64; ++j)
      gl_lds16(bG + (size_t)(w * (BN / 4) + j * 16) * K + kt,
               &Bs[db][w * (BN / 4) + j * 16][0]);
  };

  // prologue: stage B slice 0; load A-frags slice 0 into registers
  stageB(0, 0);
  bf16x8 afr[4];
#pragma unroll
  for (int tm = 0; tm < 4; ++tm) afr[tm] = *(const bf16x8*)(aR[tm]);

  for (int kt = 0; kt < K; kt += 32) {
    const int db = (kt >> 5) & 1;
    __syncthreads();  // drains own gl_lds (B slice kt) + in-flight A loads
    if (kt + 32 < K) stageB(kt + 32, db ^ 1);

    bf16x8 af[4];
#pragma unroll
    for (int tm = 0; tm < 4; ++tm) af[tm] = afr[tm];
    if (kt + 32 < K) {
#pragma unroll
      for (int tm = 0; tm < 4; ++tm)
        afr[tm] = *(const bf16x8*)(aR[tm] + kt + 32);  // prefetch next slice
    }

    bf16x8 bfr[TN];
#pragma unroll
    for (int tn = 0; tn < TN; ++tn)
      bfr[tn] = *(const bf16x8*)(&Bs[db][wn + tn * 16 + ln][kg * 8]);
#pragma unroll
    for (int tm = 0; tm < 4; ++tm)
#pragma unroll
      for (int tn = 0; tn < TN; ++tn)
        acc[tm][tn] = __builtin_amdgcn_mfma_f32_16x16x32_bf16(
            af[tm], bfr[tn], acc[tm][tn], 0, 0, 0);
  }

#pragma unroll
  for (int tm = 0; tm < 4; ++tm)
#pragma unroll
    for (int tn = 0; tn < TN; ++tn)
#pragma unroll
      for (int r = 0; r < 4; ++r)
        C[(size_t)(m0 + wm + tm * 16 + kg * 4 + r) * N + n0 + wn + tn * 16 + ln] =
            (OutT)acc[tm][tn][r];
}

// ---------------------------------------------------------------------------
// RMSNorm (per head, HD=128) + RoPE, in place on bf16 q and kv(k part).
// Q additionally pre-scaled by 1/sqrt(HD). One wave per (t, head).
// ---------------------------------------------------------------------------
__global__ __launch_bounds__(256) void norm_rope_kernel(bf16* __restrict__ q,
                                                        bf16* __restrict__ kv,
                                                        const float* __restrict__ qw,
                                                        const float* __restrict__ kw) {
  const int gw = (blockIdx.x * 256 + threadIdx.x) >> 6;
  const int lane = threadIdx.x & 63;
  bf16* base;
  const float* wgt;
  float post;
  int t;
  if (gw < cT * cH) {
    t = gw >> 5;
    int h = gw & 31;
    base = q + (size_t)t * (cH * cHD) + h * cHD;
    wgt = qw;
    post = SCALE;
  } else {
    int g2 = gw - cT * cH;
    t = g2 >> 3;
    int h = g2 & 7;
    base = kv + (size_t)t * (2 * cKV * cHD) + h * cHD;  // k part of kv buffer
    wgt = kw;
    post = 1.0f;
  }
  const int d0 = lane * 2;
  float x0 = (float)base[d0], x1 = (float)base[d0 + 1];
  float ss = x0 * x0 + x1 * x1;
#pragma unroll
  for (int off = 32; off > 0; off >>= 1) ss += __shfl_xor(ss, off, 64);
  const float rs = rsqrtf(ss * (1.0f / 128.0f) + 1e-6f);
  float y0 = x0 * rs * wgt[d0];
  float y1 = x1 * rs * wgt[d0 + 1];
  float p0 = __shfl_xor(y0, 32, 64);
  float p1 = __shfl_xor(y1, 32, 64);
  const float sgn = (lane < 32) ? -1.0f : 1.0f;  // first half gets -x2
  const int fi = d0 & 63;
  const float c1 = -19.93156856932417f / 64.0f;  // -log2(1e6)/64
  float inv0 = exp2f((float)fi * c1);
  float inv1 = exp2f((float)(fi + 1) * c1);
  float a0 = (float)t * inv0, a1 = (float)t * inv1;
  float o0 = (y0 * cosf(a0) + sgn * p0 * sinf(a0)) * post;
  float o1 = (y1 * cosf(a1) + sgn * p1 * sinf(a1)) * post;
  base[d0] = (bf16)o0;
  base[d0 + 1] = (bf16)o1;
}

// ---------------------------------------------------------------------------
// Score upper bound: S <= 128*SCALE*max|qw|*max|kw| (RMSNorm bounds row norms,
// RoPE is a rotation). Used as the fixed softmax shift C (shift-invariant).
// ---------------------------------------------------------------------------
__global__ void bound_kernel(const float* __restrict__ qw,
                             const float* __restrict__ kw,
                             float* __restrict__ cb) {
  const int lane = threadIdx.x;  // 64 threads
  float mq = fmaxf(fabsf(qw[lane]), fabsf(qw[lane + 64]));
  float mk = fmaxf(fabsf(kw[lane]), fabsf(kw[lane + 64]));
#pragma unroll
  for (int off = 32; off > 0; off >>= 1) {
    mq = fmaxf(mq, __shfl_xor(mq, off, 64));
    mk = fmaxf(mk, __shfl_xor(mk, off, 64));
  }
  if (lane == 0) *cb = 128.0f * SCALE * mq * mk + 1e-3f;
}

// ---------------------------------------------------------------------------
// MFMA flash attention (causal, GQA), fixed-C softmax (no per-tile cross-lane
// reductions, no rescaling). 128 Q rows per block, 4 waves, wave = 32 rows.
// Each Ks/VT B-frag read feeds 2 MFMAs (mt=0,1).
//
// Scheduling: LDS = 54272 B and grid = 512 -> exactly 2 resident blocks/CU,
// co-resident pair = (linear i, i+256) = same blockIdx.x. Map qt so the pair
// is work-complementary: every CU totals 36 tile-units (was 4..64 -> tail).
//
// Staging: T14 async split. K/V tile kt+1 global loads are issued right after
// the first barrier and land while tile kt computes; regs are written to LDS
// at the top of the next iteration (after the trailing barrier).
// ---------------------------------------------------------------------------
__global__ __launch_bounds__(256) void flash_kernel(const bf16* __restrict__ q,
                                                    const bf16* __restrict__ kv,
                                                    const float* __restrict__ cb,
                                                    bf16* __restrict__ out) {
  __shared__ bf16 Ks[64][136];
  __shared__ bf16 VT[128][72];
  __shared__ bf16 Ps[4][32][72];

  constexpr int KVS = 2 * cKV * cHD;  // 2048, kv row stride
  // Balanced complementary mapping (see header comment): covers every (qt,h)
  // exactly once: y<16 -> qt=15-x with h=y; y>=16 -> qt=x with h=y.
  const int qt = (blockIdx.y < 16) ? (15 - blockIdx.x) : blockIdx.x;
  const int h = blockIdx.y;
  const int qm0 = qt * 128;
  const int kh = h >> 2;  // kv head (G=4)
  const int tid = threadIdx.x;
  const int lane = tid & 63, w = tid >> 6;
  const int ln = lane & 15, kg = lane >> 4;
  const float C = *cb;
  const int row0 = qm0 + w * 32;  // wave's first Q row

  // --- preload Q A-frags: rows row0 + mt*16 + ln ---
  bf16x8 qa[2][4];
#pragma unroll
  for (int mt = 0; mt < 2; ++mt) {
    const bf16* qrow =
        q + (size_t)(row0 + mt * 16 + ln) * (cH * cHD) + h * cHD + kg * 8;
#pragma unroll
    for (int kk = 0; kk < 4; ++kk) qa[mt][kk] = *(const bf16x8*)(qrow + kk * 32);
  }

  const int sl = tid >> 2, sc = tid & 3;    // K staging: row sl, chunk sc*32
  const int vp = tid & 31, vc = tid >> 5;   // V staging: row-pair 2vp, chunk vc*16
  const bf16* kbase = kv + (size_t)sl * KVS + kh * cHD + sc * 32;
  const bf16* vbase = kv + cKV * cHD + (size_t)(2 * vp) * KVS + kh * cHD + vc * 16;

  float l_r[2][4] = {};
  f32x4 o_acc[2][8] = {};

  const int nkt = 2 * qt + 2;

  // ---- prologue: load tile 0 into staging regs ----
  bf16x8 kr[4], vr[4];
#pragma unroll
  for (int i = 0; i < 4; ++i) kr[i] = *(const bf16x8*)(kbase + i * 8);
  vr[0] = *(const bf16x8*)(vbase);
  vr[1] = *(const bf16x8*)(vbase + 8);
  vr[2] = *(const bf16x8*)(vbase + KVS);
  vr[3] = *(const bf16x8*)(vbase + KVS + 8);

  for (int kt = 0; kt < nkt; ++kt) {
    // ---- write staged K tile (loaded last iter / prologue) ----
#pragma unroll
    for (int i = 0; i < 4; ++i)
      *(bf16x8*)(&Ks[sl][sc * 32 + i * 8]) = kr[i];
    // ---- write staged V tile transposed (pair-packed b32 writes) ----
#pragma unroll
    for (int i = 0; i < 8; ++i) {
      union { bf16 hh[2]; unsigned u; } pk;
      pk.hh[0] = vr[0][i]; pk.hh[1] = vr[2][i];
      *(unsigned*)(&VT[vc * 16 + i][2 * vp]) = pk.u;
      pk.hh[0] = vr[1][i]; pk.hh[1] = vr[3][i];
      *(unsigned*)(&VT[vc * 16 + 8 + i][2 * vp]) = pk.u;
    }
    __syncthreads();

    // ---- issue next-tile global loads; they land under the compute below ----
    if (kt + 1 < nkt) {
      const bf16* kn = kbase + (size_t)(kt + 1) * 64 * KVS;
      const bf16* vn = vbase + (size_t)(kt + 1) * 64 * KVS;
#pragma unroll
      for (int i = 0; i < 4; ++i) kr[i] = *(const bf16x8*)(kn + i * 8);
      vr[0] = *(const bf16x8*)(vn);
      vr[1] = *(const bf16x8*)(vn + 8);
      vr[2] = *(const bf16x8*)(vn + KVS);
      vr[3] = *(const bf16x8*)(vn + KVS + 8);
    }

    // ---- S = Q K^T : B-frags shared across mt ----
    f32x4 s_acc[2][4] = {};
    __builtin_amdgcn_s_setprio(1);
#pragma unroll
    for (int kk = 0; kk < 4; ++kk)
#pragma unroll
      for (int nt = 0; nt < 4; ++nt) {
        bf16x8 bfr = *(const bf16x8*)(&Ks[nt * 16 + ln][kk * 32 + kg * 8]);
        s_acc[0][nt] = __builtin_amdgcn_mfma_f32_16x16x32_bf16(
            qa[0][kk], bfr, s_acc[0][nt], 0, 0, 0);
        s_acc[1][nt] = __builtin_amdgcn_mfma_f32_16x16x32_bf16(
            qa[1][kk], bfr, s_acc[1][nt], 0, 0, 0);
      }
    __builtin_amdgcn_s_setprio(0);

    // ---- P = exp(S - C) (masked on edge tiles), per-lane row sums ----
    const bool edge = (kt * 64 + 63 > row0);  // wave-uniform
#pragma unroll
    for (int mt = 0; mt < 2; ++mt)
#pragma unroll
      for (int nt = 0; nt < 4; ++nt)
#pragma unroll
        for (int r = 0; r < 4; ++r) {
          float pe = __expf(s_acc[mt][nt][r] - C);
          if (edge) {
            int col = kt * 64 + nt * 16 + ln;
            int row = row0 + mt * 16 + kg * 4 + r;
            if (col > row) pe = 0.f;
          }
          l_r[mt][r] += pe;
          Ps[w][mt * 16 + kg * 4 + r][nt * 16 + ln] = (bf16)pe;
        }

    // ---- O += P V (no rescale needed with fixed C) ----
    __builtin_amdgcn_s_setprio(1);
#pragma unroll
    for (int kk2 = 0; kk2 < 2; ++kk2) {
      bf16x8 pa0 = *(const bf16x8*)(&Ps[w][ln][kk2 * 32 + kg * 8]);
      bf16x8 pa1 = *(const bf16x8*)(&Ps[w][16 + ln][kk2 * 32 + kg * 8]);
#pragma unroll
      for (int dt = 0; dt < 8; ++dt) {
        bf16x8 vb = *(const bf16x8*)(&VT[dt * 16 + ln][kk2 * 32 + kg * 8]);
        o_acc[0][dt] = __builtin_amdgcn_mfma_f32_16x16x32_bf16(
            pa0, vb, o_acc[0][dt], 0, 0, 0);
        o_acc[1][dt] = __builtin_amdgcn_mfma_f32_16x16x32_bf16(
            pa1, vb, o_acc[1][dt], 0, 0, 0);
      }
    }
    __builtin_amdgcn_s_setprio(0);
    __syncthreads();
  }

  // ---- one final cross-lane reduction of l over ln (within kg group) ----
#pragma unroll
  for (int mt = 0; mt < 2; ++mt)
#pragma unroll
    for (int r = 0; r < 4; ++r) {
      float l = l_r[mt][r];
#pragma unroll
      for (int off = 1; off <= 8; off <<= 1) l += __shfl_xor(l, off, 64);
      l_r[mt][r] = 1.0f / l;
    }

  // ---- epilogue ----
#pragma unroll
  for (int mt = 0; mt < 2; ++mt) {
    bf16* op = out + (size_t)(row0 + mt * 16 + kg * 4) * (cH * cHD) + h * cHD + ln;
#pragma unroll
    for (int dt = 0; dt < 8; ++dt)
#pragma unroll
      for (int r = 0; r < 4; ++r)
        op[(size_t)r * (cH * cHD) + dt * 16] = (bf16)(o_acc[mt][dt][r] * l_r[mt][r]);
  }
}

// ---------------------------------------------------------------------------
// Workspace choreography (peak exactly 64 MiB, stream-ordered reuse):
//   [ 0,16M): xb (x bf16)            -> attn (after flash)
//   [16,48M): WqT (32M)              -> { WkvT [16,32M), kv [32,40M), Cb@46M }
//                                    -> WoT (after flash)
//   [48,64M): q bf16
// ---------------------------------------------------------------------------
extern "C" void kernel_launch(void* const* d_in, const int* in_sizes, int n_in,
                              void* d_out, int out_size, void* d_ws, size_t ws_size,
                              hipStream_t stream) {
  const float* x  = (const float*)d_in[0];
  const float* Wq = (const float*)d_in[1];
  const float* Wk = (const float*)d_in[2];
  const float* Wv = (const float*)d_in[3];
  const float* Wo = (const float*)d_in[4];
  const float* qw = (const float*)d_in[5];
  const float* kw = (const float*)d_in[6];
  float* out = (float*)d_out;

  char* ws = (char*)d_ws;
  bf16* xb   = (bf16*)ws;
  bf16* WqT  = (bf16*)(ws + (16u << 20));
  bf16* WkvT = (bf16*)(ws + (16u << 20));
  bf16* kvb  = (bf16*)(ws + (32u << 20));
  float* cb  = (float*)(ws + (46u << 20));
  bf16* qb   = (bf16*)(ws + (48u << 20));
  bf16* attn = (bf16*)ws;
  bf16* WoT  = (bf16*)(ws + (16u << 20));

  // x -> bf16
  convert_kernel<<<(cT * cD) / (8 * 256), 256, 0, stream>>>(x, xb);
  // Wq^T bf16; q = xb * WqT^T (bf16 out)
  convT_kernel<<<dim3(cD / 64, cD / 64), 256, 0, stream>>>(Wq, WqT, cD, cD);
  gemm_bt_kernel<128, bf16><<<dim3(cD / 128, cT / 128), 256, 0, stream>>>(
      xb, WqT, qb, cT, cD, cD);
  // Wk^T|Wv^T bf16 (fused 2048x4096); kv = xb * WkvT^T (bf16 out)
  convT_kernel<<<dim3((cKV * cHD) / 64, cD / 64), 256, 0, stream>>>(Wk, WkvT, cD, cKV * cHD);
  convT_kernel<<<dim3((cKV * cHD) / 64, cD / 64), 256, 0, stream>>>(
      Wv, WkvT + (size_t)(cKV * cHD) * cD, cD, cKV * cHD);
  gemm_bt_kernel<64, bf16><<<dim3((2 * cKV * cHD) / 64, cT / 128), 256, 0, stream>>>(
      xb, WkvT, kvb, cT, 2 * cKV * cHD, cD);
  // rmsnorm + rope (in place, bf16); softmax shift bound
  norm_rope_kernel<<<(cT * (cH + cKV)) / 4, 256, 0, stream>>>(qb, kvb, qw, kw);
  bound_kernel<<<1, 64, 0, stream>>>(qw, kw, cb);
  // flash attention -> attn bf16 (reuses xb region)
  flash_kernel<<<dim3(cT / 128, cH), 256, 0, stream>>>(qb, kvb, cb, attn);
  // Wo^T bf16 (overwrites WkvT/kv region - both dead); out = attn * WoT^T (fp32)
  convT_kernel<<<dim3(cD / 64, cD / 64), 256, 0, stream>>>(Wo, WoT, cD, cD);
  gemm_bt_kernel<128, float><<<dim3(cD / 128, cT / 128), 256, 0, stream>>>(
      attn, WoT, out, cT, cD, cD);
}

// Round 8
// 571.761 us; speedup vs baseline: 1.2630x; 1.2630x over previous
//
#include <hip/hip_runtime.h>
#include <math.h>

typedef __bf16 bf16;
typedef __bf16 bf16x8 __attribute__((ext_vector_type(8)));
typedef float f32x4 __attribute__((ext_vector_type(4)));

constexpr int cT = 2048;
constexpr int cD = 4096;
constexpr int cH = 32;
constexpr int cKV = 8;
constexpr int cHD = 128;
constexpr float SCALE = 0.08838834764831845f; // 1/sqrt(128)

// Async global->LDS, 16B per lane. LDS dest must be WAVE-UNIFORM base;
// lane i's data lands at base + i*16 (guide §5 caveat).
__device__ __forceinline__ void gl_lds16(const bf16* g, bf16* l) {
  __builtin_amdgcn_global_load_lds(
      (const __attribute__((address_space(1))) unsigned*)g,
      (__attribute__((address_space(3))) unsigned*)l, 16, 0, 0);
}

__device__ inline bf16x8 load8_cvt(const float* __restrict__ p) {
  float4 a = *(const float4*)p;
  float4 b = *(const float4*)(p + 4);
  bf16x8 r;
  r[0] = (bf16)a.x; r[1] = (bf16)a.y; r[2] = (bf16)a.z; r[3] = (bf16)a.w;
  r[4] = (bf16)b.x; r[5] = (bf16)b.y; r[6] = (bf16)b.z; r[7] = (bf16)b.w;
  return r;
}

// ---------------------------------------------------------------------------
// fp32 -> bf16 elementwise (8 elems/thread)
// ---------------------------------------------------------------------------
__global__ __launch_bounds__(256) void convert_kernel(const float* __restrict__ s,
                                                      bf16* __restrict__ d) {
  const size_t i = (size_t)(blockIdx.x * 256 + threadIdx.x) * 8;
  *(bf16x8*)(d + i) = load8_cvt(s + i);
}

// ---------------------------------------------------------------------------
// Transpose + convert: dst[c][r] = (bf16)src[r][c]. src is R x C fp32,
// dst is C x R bf16 (row stride R). 64x64 LDS tile.
// ---------------------------------------------------------------------------
__global__ __launch_bounds__(256) void convT_kernel(const float* __restrict__ src,
                                                    bf16* __restrict__ dst,
                                                    int R, int C) {
  __shared__ float t[64][65];
  const int r0 = blockIdx.y * 64, c0 = blockIdx.x * 64;
  const int tid = threadIdx.x;
  {
    const int lr = tid >> 4, lc = (tid & 15) * 4;
#pragma unroll
    for (int i = 0; i < 4; ++i) {
      float4 v4 = *(const float4*)(src + (size_t)(r0 + lr + i * 16) * C + c0 + lc);
      t[lr + i * 16][lc] = v4.x;
      t[lr + i * 16][lc + 1] = v4.y;
      t[lr + i * 16][lc + 2] = v4.z;
      t[lr + i * 16][lc + 3] = v4.w;
    }
  }
  __syncthreads();
  {
    const int c = tid >> 2, rb = (tid & 3) * 16;
#pragma unroll
    for (int half = 0; half < 2; ++half) {
      bf16x8 o;
#pragma unroll
      for (int j = 0; j < 8; ++j) o[j] = (bf16)t[rb + half * 8 + j][c];
      *(bf16x8*)(dst + (size_t)(c0 + c) * R + r0 + rb + half * 8) = o;
    }
  }
}

// ---------------------------------------------------------------------------
// 64xBN GEMM, R2/R5-proven dbuf pipeline (A-direct of R7 REVERTED: scattered
// 16-line A loads choked TA, 97->146 us; m151 reproduced: gl_lds > reg-stage).
// C[M,N] = A[M,K] * BT[N,K]^T, both bf16 K-major. BK=32, 256 threads
// (4 waves, 2x2), wave owns 32 x BN/2.
//
// Why BM=64: the R5 plateau is LOCKSTEP serialization -- all waves in a block
// exit the same barrier, burst ds_reads (MFMA idle), then burst MFMAs (LDS
// idle); ~1827 cyc/slice ~= reads(1152)+MFMA(620) serialized. Barrier-locked
// waves can't overlap (R5: occupancy 20->40% gave +3%). INDEPENDENT blocks
// can (m102: 1/CU=320 TF, 4/CU=833 TF at fixed tile; m114 co-scheduling).
// M=2048/BM=64 -> grid 1024 = 4 blocks/CU (was 2). LDS 24 KB (limit 6/CU,
// grid-capped at 4). Same per-wave economics as R5 (6 ds_read per 8 MFMA).
//
// Pipeline per K-slice: __syncthreads (drains own gl_lds via vmcnt(0)),
// issue next slice into buf^1, ds_read + MFMA on cur.
// ---------------------------------------------------------------------------
template <int BN, typename OutT>
__global__ __launch_bounds__(256) void gemm_bt_kernel(const bf16* __restrict__ A,
                                                      const bf16* __restrict__ BT,
                                                      OutT* __restrict__ C,
                                                      int M, int N, int K) {
  __shared__ __align__(16) bf16 As[2][64][32];
  __shared__ __align__(16) bf16 Bs[2][BN][32];
  constexpr int TN = BN / 32;  // n-tiles per wave

  const int tid = threadIdx.x;
  const int lane = tid & 63, w = tid >> 6;
  const int ln = lane & 15, kg = lane >> 4;
  const int m0 = blockIdx.y * 64, n0 = blockIdx.x * BN;
  const int wm = (w >> 1) * 32;       // 2 m-slots of 32 rows
  const int wn = (w & 1) * (BN / 2);  // 2 n-slots

  f32x4 acc[2][TN] = {};

  const int srow = lane >> 2;          // 0..15 within a 16-row chunk
  const int schk = (lane & 3) * 8;     // k-chunk (bf16 elems)
  const bf16* aG = A + (size_t)(m0 + srow) * K + schk;
  const bf16* bG = BT + (size_t)(n0 + srow) * K + schk;

  // Per-slice staging: wave w loads A rows [w*16, w*16+16); B rows
  // [w*(BN/4) + j*16, ...) for j < BN/64. All wave-uniform.
  auto stage = [&](int kt, int db) {
    gl_lds16(aG + (size_t)(w * 16) * K + kt, &As[db][w * 16][0]);
#pragma unroll
    for (int j = 0; j < BN / 64; ++j)
      gl_lds16(bG + (size_t)(w * (BN / 4) + j * 16) * K + kt,
               &Bs[db][w * (BN / 4) + j * 16][0]);
  };

  stage(0, 0);

  for (int kt = 0; kt < K; kt += 32) {
    const int db = (kt >> 5) & 1;
    __syncthreads();  // drains this wave's gl_lds for tile kt (vmcnt(0))
    if (kt + 32 < K) stage(kt + 32, db ^ 1);

    bf16x8 af[2], bfr[TN];
#pragma unroll
    for (int tm = 0; tm < 2; ++tm)
      af[tm] = *(const bf16x8*)(&As[db][wm + tm * 16 + ln][kg * 8]);
#pragma unroll
    for (int tn = 0; tn < TN; ++tn)
      bfr[tn] = *(const bf16x8*)(&Bs[db][wn + tn * 16 + ln][kg * 8]);
#pragma unroll
    for (int tm = 0; tm < 2; ++tm)
#pragma unroll
      for (int tn = 0; tn < TN; ++tn)
        acc[tm][tn] = __builtin_amdgcn_mfma_f32_16x16x32_bf16(
            af[tm], bfr[tn], acc[tm][tn], 0, 0, 0);
  }

#pragma unroll
  for (int tm = 0; tm < 2; ++tm)
#pragma unroll
    for (int tn = 0; tn < TN; ++tn)
#pragma unroll
      for (int r = 0; r < 4; ++r)
        C[(size_t)(m0 + wm + tm * 16 + kg * 4 + r) * N + n0 + wn + tn * 16 + ln] =
            (OutT)acc[tm][tn][r];
}

// ---------------------------------------------------------------------------
// RMSNorm (per head, HD=128) + RoPE, in place on bf16 q and kv(k part).
// Q additionally pre-scaled by 1/sqrt(HD). One wave per (t, head).
// ---------------------------------------------------------------------------
__global__ __launch_bounds__(256) void norm_rope_kernel(bf16* __restrict__ q,
                                                        bf16* __restrict__ kv,
                                                        const float* __restrict__ qw,
                                                        const float* __restrict__ kw) {
  const int gw = (blockIdx.x * 256 + threadIdx.x) >> 6;
  const int lane = threadIdx.x & 63;
  bf16* base;
  const float* wgt;
  float post;
  int t;
  if (gw < cT * cH) {
    t = gw >> 5;
    int h = gw & 31;
    base = q + (size_t)t * (cH * cHD) + h * cHD;
    wgt = qw;
    post = SCALE;
  } else {
    int g2 = gw - cT * cH;
    t = g2 >> 3;
    int h = g2 & 7;
    base = kv + (size_t)t * (2 * cKV * cHD) + h * cHD;  // k part of kv buffer
    wgt = kw;
    post = 1.0f;
  }
  const int d0 = lane * 2;
  float x0 = (float)base[d0], x1 = (float)base[d0 + 1];
  float ss = x0 * x0 + x1 * x1;
#pragma unroll
  for (int off = 32; off > 0; off >>= 1) ss += __shfl_xor(ss, off, 64);
  const float rs = rsqrtf(ss * (1.0f / 128.0f) + 1e-6f);
  float y0 = x0 * rs * wgt[d0];
  float y1 = x1 * rs * wgt[d0 + 1];
  float p0 = __shfl_xor(y0, 32, 64);
  float p1 = __shfl_xor(y1, 32, 64);
  const float sgn = (lane < 32) ? -1.0f : 1.0f;  // first half gets -x2
  const int fi = d0 & 63;
  const float c1 = -19.93156856932417f / 64.0f;  // -log2(1e6)/64
  float inv0 = exp2f((float)fi * c1);
  float inv1 = exp2f((float)(fi + 1) * c1);
  float a0 = (float)t * inv0, a1 = (float)t * inv1;
  float o0 = (y0 * cosf(a0) + sgn * p0 * sinf(a0)) * post;
  float o1 = (y1 * cosf(a1) + sgn * p1 * sinf(a1)) * post;
  base[d0] = (bf16)o0;
  base[d0 + 1] = (bf16)o1;
}

// ---------------------------------------------------------------------------
// Score upper bound: S <= 128*SCALE*max|qw|*max|kw| (RMSNorm bounds row norms,
// RoPE is a rotation). Used as the fixed softmax shift C (shift-invariant).
// ---------------------------------------------------------------------------
__global__ void bound_kernel(const float* __restrict__ qw,
                             const float* __restrict__ kw,
                             float* __restrict__ cb) {
  const int lane = threadIdx.x;  // 64 threads
  float mq = fmaxf(fabsf(qw[lane]), fabsf(qw[lane + 64]));
  float mk = fmaxf(fabsf(kw[lane]), fabsf(kw[lane + 64]));
#pragma unroll
  for (int off = 32; off > 0; off >>= 1) {
    mq = fmaxf(mq, __shfl_xor(mq, off, 64));
    mk = fmaxf(mk, __shfl_xor(mk, off, 64));
  }
  if (lane == 0) *cb = 128.0f * SCALE * mq * mk + 1e-3f;
}

// ---------------------------------------------------------------------------
// MFMA flash attention (causal, GQA), fixed-C softmax (no per-tile cross-lane
// reductions, no rescaling). 128 Q rows per block, 4 waves, wave = 32 rows.
// Each Ks/VT B-frag read feeds 2 MFMAs (mt=0,1).
//
// Scheduling: LDS = 54272 B and grid = 512 -> exactly 2 resident blocks/CU,
// co-resident pair = (linear i, i+256) = same blockIdx.x. Map qt so the pair
// is work-complementary: every CU totals 36 tile-units (was 4..64 -> tail).
//
// Staging: T14 async split. K/V tile kt+1 global loads are issued right after
// the first barrier and land while tile kt computes; regs are written to LDS
// at the top of the next iteration (after the trailing barrier).
// ---------------------------------------------------------------------------
__global__ __launch_bounds__(256) void flash_kernel(const bf16* __restrict__ q,
                                                    const bf16* __restrict__ kv,
                                                    const float* __restrict__ cb,
                                                    bf16* __restrict__ out) {
  __shared__ bf16 Ks[64][136];
  __shared__ bf16 VT[128][72];
  __shared__ bf16 Ps[4][32][72];

  constexpr int KVS = 2 * cKV * cHD;  // 2048, kv row stride
  // Balanced complementary mapping (see header comment): covers every (qt,h)
  // exactly once: y<16 -> qt=15-x with h=y; y>=16 -> qt=x with h=y.
  const int qt = (blockIdx.y < 16) ? (15 - blockIdx.x) : blockIdx.x;
  const int h = blockIdx.y;
  const int qm0 = qt * 128;
  const int kh = h >> 2;  // kv head (G=4)
  const int tid = threadIdx.x;
  const int lane = tid & 63, w = tid >> 6;
  const int ln = lane & 15, kg = lane >> 4;
  const float C = *cb;
  const int row0 = qm0 + w * 32;  // wave's first Q row

  // --- preload Q A-frags: rows row0 + mt*16 + ln ---
  bf16x8 qa[2][4];
#pragma unroll
  for (int mt = 0; mt < 2; ++mt) {
    const bf16* qrow =
        q + (size_t)(row0 + mt * 16 + ln) * (cH * cHD) + h * cHD + kg * 8;
#pragma unroll
    for (int kk = 0; kk < 4; ++kk) qa[mt][kk] = *(const bf16x8*)(qrow + kk * 32);
  }

  const int sl = tid >> 2, sc = tid & 3;    // K staging: row sl, chunk sc*32
  const int vp = tid & 31, vc = tid >> 5;   // V staging: row-pair 2vp, chunk vc*16
  const bf16* kbase = kv + (size_t)sl * KVS + kh * cHD + sc * 32;
  const bf16* vbase = kv + cKV * cHD + (size_t)(2 * vp) * KVS + kh * cHD + vc * 16;

  float l_r[2][4] = {};
  f32x4 o_acc[2][8] = {};

  const int nkt = 2 * qt + 2;

  // ---- prologue: load tile 0 into staging regs ----
  bf16x8 kr[4], vr[4];
#pragma unroll
  for (int i = 0; i < 4; ++i) kr[i] = *(const bf16x8*)(kbase + i * 8);
  vr[0] = *(const bf16x8*)(vbase);
  vr[1] = *(const bf16x8*)(vbase + 8);
  vr[2] = *(const bf16x8*)(vbase + KVS);
  vr[3] = *(const bf16x8*)(vbase + KVS + 8);

  for (int kt = 0; kt < nkt; ++kt) {
    // ---- write staged K tile (loaded last iter / prologue) ----
#pragma unroll
    for (int i = 0; i < 4; ++i)
      *(bf16x8*)(&Ks[sl][sc * 32 + i * 8]) = kr[i];
    // ---- write staged V tile transposed (pair-packed b32 writes) ----
#pragma unroll
    for (int i = 0; i < 8; ++i) {
      union { bf16 hh[2]; unsigned u; } pk;
      pk.hh[0] = vr[0][i]; pk.hh[1] = vr[2][i];
      *(unsigned*)(&VT[vc * 16 + i][2 * vp]) = pk.u;
      pk.hh[0] = vr[1][i]; pk.hh[1] = vr[3][i];
      *(unsigned*)(&VT[vc * 16 + 8 + i][2 * vp]) = pk.u;
    }
    __syncthreads();

    // ---- issue next-tile global loads; they land under the compute below ----
    if (kt + 1 < nkt) {
      const bf16* kn = kbase + (size_t)(kt + 1) * 64 * KVS;
      const bf16* vn = vbase + (size_t)(kt + 1) * 64 * KVS;
#pragma unroll
      for (int i = 0; i < 4; ++i) kr[i] = *(const bf16x8*)(kn + i * 8);
      vr[0] = *(const bf16x8*)(vn);
      vr[1] = *(const bf16x8*)(vn + 8);
      vr[2] = *(const bf16x8*)(vn + KVS);
      vr[3] = *(const bf16x8*)(vn + KVS + 8);
    }

    // ---- S = Q K^T : B-frags shared across mt ----
    f32x4 s_acc[2][4] = {};
    __builtin_amdgcn_s_setprio(1);
#pragma unroll
    for (int kk = 0; kk < 4; ++kk)
#pragma unroll
      for (int nt = 0; nt < 4; ++nt) {
        bf16x8 bfr = *(const bf16x8*)(&Ks[nt * 16 + ln][kk * 32 + kg * 8]);
        s_acc[0][nt] = __builtin_amdgcn_mfma_f32_16x16x32_bf16(
            qa[0][kk], bfr, s_acc[0][nt], 0, 0, 0);
        s_acc[1][nt] = __builtin_amdgcn_mfma_f32_16x16x32_bf16(
            qa[1][kk], bfr, s_acc[1][nt], 0, 0, 0);
      }
    __builtin_amdgcn_s_setprio(0);

    // ---- P = exp(S - C) (masked on edge tiles), per-lane row sums ----
    const bool edge = (kt * 64 + 63 > row0);  // wave-uniform
#pragma unroll
    for (int mt = 0; mt < 2; ++mt)
#pragma unroll
      for (int nt = 0; nt < 4; ++nt)
#pragma unroll
        for (int r = 0; r < 4; ++r) {
          float pe = __expf(s_acc[mt][nt][r] - C);
          if (edge) {
            int col = kt * 64 + nt * 16 + ln;
            int row = row0 + mt * 16 + kg * 4 + r;
            if (col > row) pe = 0.f;
          }
          l_r[mt][r] += pe;
          Ps[w][mt * 16 + kg * 4 + r][nt * 16 + ln] = (bf16)pe;
        }

    // ---- O += P V (no rescale needed with fixed C) ----
    __builtin_amdgcn_s_setprio(1);
#pragma unroll
    for (int kk2 = 0; kk2 < 2; ++kk2) {
      bf16x8 pa0 = *(const bf16x8*)(&Ps[w][ln][kk2 * 32 + kg * 8]);
      bf16x8 pa1 = *(const bf16x8*)(&Ps[w][16 + ln][kk2 * 32 + kg * 8]);
#pragma unroll
      for (int dt = 0; dt < 8; ++dt) {
        bf16x8 vb = *(const bf16x8*)(&VT[dt * 16 + ln][kk2 * 32 + kg * 8]);
        o_acc[0][dt] = __builtin_amdgcn_mfma_f32_16x16x32_bf16(
            pa0, vb, o_acc[0][dt], 0, 0, 0);
        o_acc[1][dt] = __builtin_amdgcn_mfma_f32_16x16x32_bf16(
            pa1, vb, o_acc[1][dt], 0, 0, 0);
      }
    }
    __builtin_amdgcn_s_setprio(0);
    __syncthreads();
  }

  // ---- one final cross-lane reduction of l over ln (within kg group) ----
#pragma unroll
  for (int mt = 0; mt < 2; ++mt)
#pragma unroll
    for (int r = 0; r < 4; ++r) {
      float l = l_r[mt][r];
#pragma unroll
      for (int off = 1; off <= 8; off <<= 1) l += __shfl_xor(l, off, 64);
      l_r[mt][r] = 1.0f / l;
    }

  // ---- epilogue ----
#pragma unroll
  for (int mt = 0; mt < 2; ++mt) {
    bf16* op = out + (size_t)(row0 + mt * 16 + kg * 4) * (cH * cHD) + h * cHD + ln;
#pragma unroll
    for (int dt = 0; dt < 8; ++dt)
#pragma unroll
      for (int r = 0; r < 4; ++r)
        op[(size_t)r * (cH * cHD) + dt * 16] = (bf16)(o_acc[mt][dt][r] * l_r[mt][r]);
  }
}

// ---------------------------------------------------------------------------
// Workspace choreography (peak exactly 64 MiB, stream-ordered reuse):
//   [ 0,16M): xb (x bf16)            -> attn (after flash)
//   [16,48M): WqT (32M)              -> { WkvT [16,32M), kv [32,40M), Cb@46M }
//                                    -> WoT (after flash)
//   [48,64M): q bf16
// ---------------------------------------------------------------------------
extern "C" void kernel_launch(void* const* d_in, const int* in_sizes, int n_in,
                              void* d_out, int out_size, void* d_ws, size_t ws_size,
                              hipStream_t stream) {
  const float* x  = (const float*)d_in[0];
  const float* Wq = (const float*)d_in[1];
  const float* Wk = (const float*)d_in[2];
  const float* Wv = (const float*)d_in[3];
  const float* Wo = (const float*)d_in[4];
  const float* qw = (const float*)d_in[5];
  const float* kw = (const float*)d_in[6];
  float* out = (float*)d_out;

  char* ws = (char*)d_ws;
  bf16* xb   = (bf16*)ws;
  bf16* WqT  = (bf16*)(ws + (16u << 20));
  bf16* WkvT = (bf16*)(ws + (16u << 20));
  bf16* kvb  = (bf16*)(ws + (32u << 20));
  float* cb  = (float*)(ws + (46u << 20));
  bf16* qb   = (bf16*)(ws + (48u << 20));
  bf16* attn = (bf16*)ws;
  bf16* WoT  = (bf16*)(ws + (16u << 20));

  // x -> bf16
  convert_kernel<<<(cT * cD) / (8 * 256), 256, 0, stream>>>(x, xb);
  // Wq^T bf16; q = xb * WqT^T (bf16 out)
  convT_kernel<<<dim3(cD / 64, cD / 64), 256, 0, stream>>>(Wq, WqT, cD, cD);
  gemm_bt_kernel<128, bf16><<<dim3(cD / 128, cT / 64), 256, 0, stream>>>(
      xb, WqT, qb, cT, cD, cD);
  // Wk^T|Wv^T bf16 (fused 2048x4096); kv = xb * WkvT^T (bf16 out)
  convT_kernel<<<dim3((cKV * cHD) / 64, cD / 64), 256, 0, stream>>>(Wk, WkvT, cD, cKV * cHD);
  convT_kernel<<<dim3((cKV * cHD) / 64, cD / 64), 256, 0, stream>>>(
      Wv, WkvT + (size_t)(cKV * cHD) * cD, cD, cKV * cHD);
  gemm_bt_kernel<64, bf16><<<dim3((2 * cKV * cHD) / 64, cT / 64), 256, 0, stream>>>(
      xb, WkvT, kvb, cT, 2 * cKV * cHD, cD);
  // rmsnorm + rope (in place, bf16); softmax shift bound
  norm_rope_kernel<<<(cT * (cH + cKV)) / 4, 256, 0, stream>>>(qb, kvb, qw, kw);
  bound_kernel<<<1, 64, 0, stream>>>(qw, kw, cb);
  // flash attention -> attn bf16 (reuses xb region)
  flash_kernel<<<dim3(cT / 128, cH), 256, 0, stream>>>(qb, kvb, cb, attn);
  // Wo^T bf16 (overwrites WkvT/kv region - both dead); out = attn * WoT^T (fp32)
  convT_kernel<<<dim3(cD / 64, cD / 64), 256, 0, stream>>>(Wo, WoT, cD, cD);
  gemm_bt_kernel<128, float><<<dim3(cD / 128, cT / 64), 256, 0, stream>>>(
      attn, WoT, out, cT, cD, cD);
}

// Round 10
// 516.668 us; speedup vs baseline: 1.3977x; 1.1066x over previous
//
#include <hip/hip_runtime.h>
#include <math.h>

typedef __bf16 bf16;
typedef __bf16 bf16x8 __attribute__((ext_vector_type(8)));
typedef float f32x4 __attribute__((ext_vector_type(4)));

constexpr int cT = 2048;
constexpr int cD = 4096;
constexpr int cH = 32;
constexpr int cKV = 8;
constexpr int cHD = 128;
constexpr float SCALE = 0.08838834764831845f; // 1/sqrt(128)

// Async global->LDS, 16B per lane. LDS dest must be WAVE-UNIFORM base;
// lane i's data lands at base + i*16 (guide §5 caveat). The GLOBAL source
// address IS per-lane -> swizzled LDS layouts are achieved by pre-swizzling
// the per-lane global address while keeping LDS linear (m173 pattern).
__device__ __forceinline__ void gl_lds16(const bf16* g, bf16* l) {
  __builtin_amdgcn_global_load_lds(
      (const __attribute__((address_space(1))) unsigned*)g,
      (__attribute__((address_space(3))) unsigned*)l, 16, 0, 0);
}

__device__ inline bf16x8 load8_cvt(const float* __restrict__ p) {
  float4 a = *(const float4*)p;
  float4 b = *(const float4*)(p + 4);
  bf16x8 r;
  r[0] = (bf16)a.x; r[1] = (bf16)a.y; r[2] = (bf16)a.z; r[3] = (bf16)a.w;
  r[4] = (bf16)b.x; r[5] = (bf16)b.y; r[6] = (bf16)b.z; r[7] = (bf16)b.w;
  return r;
}

// ---------------------------------------------------------------------------
// fp32 -> bf16 elementwise (8 elems/thread)
// ---------------------------------------------------------------------------
__global__ __launch_bounds__(256) void convert_kernel(const float* __restrict__ s,
                                                      bf16* __restrict__ d) {
  const size_t i = (size_t)(blockIdx.x * 256 + threadIdx.x) * 8;
  *(bf16x8*)(d + i) = load8_cvt(s + i);
}

// ---------------------------------------------------------------------------
// Transpose + convert: dst[c][r] = (bf16)src[r][c]. src is R x C fp32,
// dst is C x R bf16 (row stride R). 64x64 LDS tile.
// ---------------------------------------------------------------------------
__global__ __launch_bounds__(256) void convT_kernel(const float* __restrict__ src,
                                                    bf16* __restrict__ dst,
                                                    int R, int C) {
  __shared__ float t[64][65];
  const int r0 = blockIdx.y * 64, c0 = blockIdx.x * 64;
  const int tid = threadIdx.x;
  {
    const int lr = tid >> 4, lc = (tid & 15) * 4;
#pragma unroll
    for (int i = 0; i < 4; ++i) {
      float4 v4 = *(const float4*)(src + (size_t)(r0 + lr + i * 16) * C + c0 + lc);
      t[lr + i * 16][lc] = v4.x;
      t[lr + i * 16][lc + 1] = v4.y;
      t[lr + i * 16][lc + 2] = v4.z;
      t[lr + i * 16][lc + 3] = v4.w;
    }
  }
  __syncthreads();
  {
    const int c = tid >> 2, rb = (tid & 3) * 16;
#pragma unroll
    for (int half = 0; half < 2; ++half) {
      bf16x8 o;
#pragma unroll
      for (int j = 0; j < 8; ++j) o[j] = (bf16)t[rb + half * 8 + j][c];
      *(bf16x8*)(dst + (size_t)(c0 + c) * R + r0 + rb + half * 8) = o;
    }
  }
}

// ---------------------------------------------------------------------------
// 128xBN GEMM, BK=64, XOR-swizzled LDS. C[M,N] = A[M,K]*BT[N,K]^T, bf16
// K-major. 256 threads (4 waves, 2x2), wave owns 64 x BN/2 (best read
// economics: 0.5 ds_read_b128 per MFMA).
//
// R5/R8 post-mortem: 3-point TLP scan (8/16/16 waves-per-CU in different
// arrangements) all landed 97-108 us -> TLP is not the lever; the invariant
// tax is 128 barrier+drain slices with a too-thin compute phase. Fix:
// BK 32->64 halves the drain count and doubles the MFMA cluster per phase.
// m132's BK-widening failure (LDS occupancy loss 3->2) doesn't apply: we
// are grid-capped at 2 blocks/CU either way.
//
// BK=64 makes LDS rows 128 B -> naive fragment reads are 16-way bank
// conflicts (guide §6 G4). Rule #21 fix (both-sides involution): staging
// pre-swizzles the per-lane GLOBAL chunk (kchunk ^= row&7 within each
// 8-row/1024B gl_lds group; a permutation within the 128B row, coalescing
// preserved), LDS stays linear, reads apply the same XOR (col ^ (ln&7)).
// Result: uniform 8 lanes/bank-quad = the free minimum.
//
// Pipeline per K-slice: __syncthreads (drains own gl_lds via vmcnt(0)),
// issue next slice into buf^1, 16 ds_read + 32 MFMA on cur.
// ---------------------------------------------------------------------------
template <int BN, typename OutT>
__global__ __launch_bounds__(256) void gemm_bt_kernel(const bf16* __restrict__ A,
                                                      const bf16* __restrict__ BT,
                                                      OutT* __restrict__ C,
                                                      int M, int N, int K) {
  __shared__ __align__(16) bf16 As[2][128][64];
  __shared__ __align__(16) bf16 Bs[2][BN][64];
  constexpr int TN = BN / 32;  // n-tiles per wave

  const int tid = threadIdx.x;
  const int lane = tid & 63, w = tid >> 6;
  const int ln = lane & 15, kg = lane >> 4;
  const int m0 = blockIdx.y * 128, n0 = blockIdx.x * BN;
  const int wm = (w >> 1) * 64;
  const int wn = (w & 1) * (BN / 2);

  f32x4 acc[4][TN] = {};

  // Staging: each gl_lds covers 8 rows x 128 B. Per-lane source:
  // row = base + (lane>>3), k-chunk = (lane&7) ^ (lane>>3)  [swizzle].
  const int srow8 = lane >> 3;
  const int schk8 = (((lane & 7) ^ (lane >> 3)) & 7) * 8;  // elems
  const bf16* aG = A + (size_t)(m0 + srow8) * K + schk8;
  const bf16* bG = BT + (size_t)(n0 + srow8) * K + schk8;

  auto stage = [&](int kt, int db) {
#pragma unroll
    for (int g = 0; g < 4; ++g)  // A: wave w stages rows [w*32, w*32+32)
      gl_lds16(aG + (size_t)(w * 32 + g * 8) * K + kt, &As[db][w * 32 + g * 8][0]);
#pragma unroll
    for (int g = 0; g < BN / 32; ++g)  // B: rows [w*(BN/4), +BN/4)
      gl_lds16(bG + (size_t)(w * (BN / 4) + g * 8) * K + kt,
               &Bs[db][w * (BN / 4) + g * 8][0]);
  };

  stage(0, 0);

  for (int kt = 0; kt < K; kt += 64) {
    const int db = (kt >> 6) & 1;
    __syncthreads();  // drains this wave's gl_lds for slice kt (vmcnt(0))
    if (kt + 64 < K) stage(kt + 64, db ^ 1);

    // LDS[r][j] holds global chunk j ^ (r&7); reader wants col kk*4+kg of
    // row wm+tm*16+ln -> LDS col (kk*4+kg) ^ (ln&7).
    bf16x8 af[4][2], bfr[TN][2];
#pragma unroll
    for (int tm = 0; tm < 4; ++tm)
#pragma unroll
      for (int kk = 0; kk < 2; ++kk)
        af[tm][kk] = *(const bf16x8*)(
            &As[db][wm + tm * 16 + ln][((kk * 4 + kg) ^ (ln & 7)) * 8]);
#pragma unroll
    for (int tn = 0; tn < TN; ++tn)
#pragma unroll
      for (int kk = 0; kk < 2; ++kk)
        bfr[tn][kk] = *(const bf16x8*)(
            &Bs[db][wn + tn * 16 + ln][((kk * 4 + kg) ^ (ln & 7)) * 8]);
#pragma unroll
    for (int kk = 0; kk < 2; ++kk)
#pragma unroll
      for (int tm = 0; tm < 4; ++tm)
#pragma unroll
        for (int tn = 0; tn < TN; ++tn)
          acc[tm][tn] = __builtin_amdgcn_mfma_f32_16x16x32_bf16(
              af[tm][kk], bfr[tn][kk], acc[tm][tn], 0, 0, 0);
  }

#pragma unroll
  for (int tm = 0; tm < 4; ++tm)
#pragma unroll
    for (int tn = 0; tn < TN; ++tn)
#pragma unroll
      for (int r = 0; r < 4; ++r)
        C[(size_t)(m0 + wm + tm * 16 + kg * 4 + r) * N + n0 + wn + tn * 16 + ln] =
            (OutT)acc[tm][tn][r];
}

// ---------------------------------------------------------------------------
// RMSNorm (per head, HD=128) + RoPE, in place on bf16 q and kv(k part).
// Q additionally pre-scaled by 1/sqrt(HD). One wave per (t, head).
// ---------------------------------------------------------------------------
__global__ __launch_bounds__(256) void norm_rope_kernel(bf16* __restrict__ q,
                                                        bf16* __restrict__ kv,
                                                        const float* __restrict__ qw,
                                                        const float* __restrict__ kw) {
  const int gw = (blockIdx.x * 256 + threadIdx.x) >> 6;
  const int lane = threadIdx.x & 63;
  bf16* base;
  const float* wgt;
  float post;
  int t;
  if (gw < cT * cH) {
    t = gw >> 5;
    int h = gw & 31;
    base = q + (size_t)t * (cH * cHD) + h * cHD;
    wgt = qw;
    post = SCALE;
  } else {
    int g2 = gw - cT * cH;
    t = g2 >> 3;
    int h = g2 & 7;
    base = kv + (size_t)t * (2 * cKV * cHD) + h * cHD;  // k part of kv buffer
    wgt = kw;
    post = 1.0f;
  }
  const int d0 = lane * 2;
  float x0 = (float)base[d0], x1 = (float)base[d0 + 1];
  float ss = x0 * x0 + x1 * x1;
#pragma unroll
  for (int off = 32; off > 0; off >>= 1) ss += __shfl_xor(ss, off, 64);
  const float rs = rsqrtf(ss * (1.0f / 128.0f) + 1e-6f);
  float y0 = x0 * rs * wgt[d0];
  float y1 = x1 * rs * wgt[d0 + 1];
  float p0 = __shfl_xor(y0, 32, 64);
  float p1 = __shfl_xor(y1, 32, 64);
  const float sgn = (lane < 32) ? -1.0f : 1.0f;  // first half gets -x2
  const int fi = d0 & 63;
  const float c1 = -19.93156856932417f / 64.0f;  // -log2(1e6)/64
  float inv0 = exp2f((float)fi * c1);
  float inv1 = exp2f((float)(fi + 1) * c1);
  float a0 = (float)t * inv0, a1 = (float)t * inv1;
  float o0 = (y0 * cosf(a0) + sgn * p0 * sinf(a0)) * post;
  float o1 = (y1 * cosf(a1) + sgn * p1 * sinf(a1)) * post;
  base[d0] = (bf16)o0;
  base[d0 + 1] = (bf16)o1;
}

// ---------------------------------------------------------------------------
// Score upper bound: S <= 128*SCALE*max|qw|*max|kw| (RMSNorm bounds row norms,
// RoPE is a rotation). Used as the fixed softmax shift C (shift-invariant).
// ---------------------------------------------------------------------------
__global__ void bound_kernel(const float* __restrict__ qw,
                             const float* __restrict__ kw,
                             float* __restrict__ cb) {
  const int lane = threadIdx.x;  // 64 threads
  float mq = fmaxf(fabsf(qw[lane]), fabsf(qw[lane + 64]));
  float mk = fmaxf(fabsf(kw[lane]), fabsf(kw[lane + 64]));
#pragma unroll
  for (int off = 32; off > 0; off >>= 1) {
    mq = fmaxf(mq, __shfl_xor(mq, off, 64));
    mk = fmaxf(mk, __shfl_xor(mk, off, 64));
  }
  if (lane == 0) *cb = 128.0f * SCALE * mq * mk + 1e-3f;
}

// ---------------------------------------------------------------------------
// MFMA flash attention (causal, GQA), fixed-C softmax (no per-tile cross-lane
// reductions, no rescaling). 128 Q rows per block, 4 waves, wave = 32 rows.
// Each Ks/VT B-frag read feeds 2 MFMAs (mt=0,1).
//
// Scheduling: LDS = 54272 B and grid = 512 -> exactly 2 resident blocks/CU,
// co-resident pair = (linear i, i+256) = same blockIdx.x. Map qt so the pair
// is work-complementary: every CU totals 36 tile-units (was 4..64 -> tail).
//
// Staging: T14 async split. K/V tile kt+1 global loads are issued right after
// the first barrier and land while tile kt computes; regs are written to LDS
// at the top of the next iteration (after the trailing barrier).
// ---------------------------------------------------------------------------
__global__ __launch_bounds__(256) void flash_kernel(const bf16* __restrict__ q,
                                                    const bf16* __restrict__ kv,
                                                    const float* __restrict__ cb,
                                                    bf16* __restrict__ out) {
  __shared__ bf16 Ks[64][136];
  __shared__ bf16 VT[128][72];
  __shared__ bf16 Ps[4][32][72];

  constexpr int KVS = 2 * cKV * cHD;  // 2048, kv row stride
  // Balanced complementary mapping (see header comment): covers every (qt,h)
  // exactly once: y<16 -> qt=15-x with h=y; y>=16 -> qt=x with h=y.
  const int qt = (blockIdx.y < 16) ? (15 - blockIdx.x) : blockIdx.x;
  const int h = blockIdx.y;
  const int qm0 = qt * 128;
  const int kh = h >> 2;  // kv head (G=4)
  const int tid = threadIdx.x;
  const int lane = tid & 63, w = tid >> 6;
  const int ln = lane & 15, kg = lane >> 4;
  const float C = *cb;
  const int row0 = qm0 + w * 32;  // wave's first Q row

  // --- preload Q A-frags: rows row0 + mt*16 + ln ---
  bf16x8 qa[2][4];
#pragma unroll
  for (int mt = 0; mt < 2; ++mt) {
    const bf16* qrow =
        q + (size_t)(row0 + mt * 16 + ln) * (cH * cHD) + h * cHD + kg * 8;
#pragma unroll
    for (int kk = 0; kk < 4; ++kk) qa[mt][kk] = *(const bf16x8*)(qrow + kk * 32);
  }

  const int sl = tid >> 2, sc = tid & 3;    // K staging: row sl, chunk sc*32
  const int vp = tid & 31, vc = tid >> 5;   // V staging: row-pair 2vp, chunk vc*16
  const bf16* kbase = kv + (size_t)sl * KVS + kh * cHD + sc * 32;
  const bf16* vbase = kv + cKV * cHD + (size_t)(2 * vp) * KVS + kh * cHD + vc * 16;

  float l_r[2][4] = {};
  f32x4 o_acc[2][8] = {};

  const int nkt = 2 * qt + 2;

  // ---- prologue: load tile 0 into staging regs ----
  bf16x8 kr[4], vr[4];
#pragma unroll
  for (int i = 0; i < 4; ++i) kr[i] = *(const bf16x8*)(kbase + i * 8);
  vr[0] = *(const bf16x8*)(vbase);
  vr[1] = *(const bf16x8*)(vbase + 8);
  vr[2] = *(const bf16x8*)(vbase + KVS);
  vr[3] = *(const bf16x8*)(vbase + KVS + 8);

  for (int kt = 0; kt < nkt; ++kt) {
    // ---- write staged K tile (loaded last iter / prologue) ----
#pragma unroll
    for (int i = 0; i < 4; ++i)
      *(bf16x8*)(&Ks[sl][sc * 32 + i * 8]) = kr[i];
    // ---- write staged V tile transposed (pair-packed b32 writes) ----
#pragma unroll
    for (int i = 0; i < 8; ++i) {
      union { bf16 hh[2]; unsigned u; } pk;
      pk.hh[0] = vr[0][i]; pk.hh[1] = vr[2][i];
      *(unsigned*)(&VT[vc * 16 + i][2 * vp]) = pk.u;
      pk.hh[0] = vr[1][i]; pk.hh[1] = vr[3][i];
      *(unsigned*)(&VT[vc * 16 + 8 + i][2 * vp]) = pk.u;
    }
    __syncthreads();

    // ---- issue next-tile global loads; they land under the compute below ----
    if (kt + 1 < nkt) {
      const bf16* kn = kbase + (size_t)(kt + 1) * 64 * KVS;
      const bf16* vn = vbase + (size_t)(kt + 1) * 64 * KVS;
#pragma unroll
      for (int i = 0; i < 4; ++i) kr[i] = *(const bf16x8*)(kn + i * 8);
      vr[0] = *(const bf16x8*)(vn);
      vr[1] = *(const bf16x8*)(vn + 8);
      vr[2] = *(const bf16x8*)(vn + KVS);
      vr[3] = *(const bf16x8*)(vn + KVS + 8);
    }

    // ---- S = Q K^T : B-frags shared across mt ----
    f32x4 s_acc[2][4] = {};
    __builtin_amdgcn_s_setprio(1);
#pragma unroll
    for (int kk = 0; kk < 4; ++kk)
#pragma unroll
      for (int nt = 0; nt < 4; ++nt) {
        bf16x8 bfr = *(const bf16x8*)(&Ks[nt * 16 + ln][kk * 32 + kg * 8]);
        s_acc[0][nt] = __builtin_amdgcn_mfma_f32_16x16x32_bf16(
            qa[0][kk], bfr, s_acc[0][nt], 0, 0, 0);
        s_acc[1][nt] = __builtin_amdgcn_mfma_f32_16x16x32_bf16(
            qa[1][kk], bfr, s_acc[1][nt], 0, 0, 0);
      }
    __builtin_amdgcn_s_setprio(0);

    // ---- P = exp(S - C) (masked on edge tiles), per-lane row sums ----
    const bool edge = (kt * 64 + 63 > row0);  // wave-uniform
#pragma unroll
    for (int mt = 0; mt < 2; ++mt)
#pragma unroll
      for (int nt = 0; nt < 4; ++nt)
#pragma unroll
        for (int r = 0; r < 4; ++r) {
          float pe = __expf(s_acc[mt][nt][r] - C);
          if (edge) {
            int col = kt * 64 + nt * 16 + ln;
            int row = row0 + mt * 16 + kg * 4 + r;
            if (col > row) pe = 0.f;
          }
          l_r[mt][r] += pe;
          Ps[w][mt * 16 + kg * 4 + r][nt * 16 + ln] = (bf16)pe;
        }

    // ---- O += P V (no rescale needed with fixed C) ----
    __builtin_amdgcn_s_setprio(1);
#pragma unroll
    for (int kk2 = 0; kk2 < 2; ++kk2) {
      bf16x8 pa0 = *(const bf16x8*)(&Ps[w][ln][kk2 * 32 + kg * 8]);
      bf16x8 pa1 = *(const bf16x8*)(&Ps[w][16 + ln][kk2 * 32 + kg * 8]);
#pragma unroll
      for (int dt = 0; dt < 8; ++dt) {
        bf16x8 vb = *(const bf16x8*)(&VT[dt * 16 + ln][kk2 * 32 + kg * 8]);
        o_acc[0][dt] = __builtin_amdgcn_mfma_f32_16x16x32_bf16(
            pa0, vb, o_acc[0][dt], 0, 0, 0);
        o_acc[1][dt] = __builtin_amdgcn_mfma_f32_16x16x32_bf16(
            pa1, vb, o_acc[1][dt], 0, 0, 0);
      }
    }
    __builtin_amdgcn_s_setprio(0);
    __syncthreads();
  }

  // ---- one final cross-lane reduction of l over ln (within kg group) ----
#pragma unroll
  for (int mt = 0; mt < 2; ++mt)
#pragma unroll
    for (int r = 0; r < 4; ++r) {
      float l = l_r[mt][r];
#pragma unroll
      for (int off = 1; off <= 8; off <<= 1) l += __shfl_xor(l, off, 64);
      l_r[mt][r] = 1.0f / l;
    }

  // ---- epilogue ----
#pragma unroll
  for (int mt = 0; mt < 2; ++mt) {
    bf16* op = out + (size_t)(row0 + mt * 16 + kg * 4) * (cH * cHD) + h * cHD + ln;
#pragma unroll
    for (int dt = 0; dt < 8; ++dt)
#pragma unroll
      for (int r = 0; r < 4; ++r)
        op[(size_t)r * (cH * cHD) + dt * 16] = (bf16)(o_acc[mt][dt][r] * l_r[mt][r]);
  }
}

// ---------------------------------------------------------------------------
// Workspace choreography (peak exactly 64 MiB, stream-ordered reuse):
//   [ 0,16M): xb (x bf16)            -> attn (after flash)
//   [16,48M): WqT (32M)              -> { WkvT [16,32M), kv [32,40M), Cb@46M }
//                                    -> WoT (after flash)
//   [48,64M): q bf16
// ---------------------------------------------------------------------------
extern "C" void kernel_launch(void* const* d_in, const int* in_sizes, int n_in,
                              void* d_out, int out_size, void* d_ws, size_t ws_size,
                              hipStream_t stream) {
  const float* x  = (const float*)d_in[0];
  const float* Wq = (const float*)d_in[1];
  const float* Wk = (const float*)d_in[2];
  const float* Wv = (const float*)d_in[3];
  const float* Wo = (const float*)d_in[4];
  const float* qw = (const float*)d_in[5];
  const float* kw = (const float*)d_in[6];
  float* out = (float*)d_out;

  char* ws = (char*)d_ws;
  bf16* xb   = (bf16*)ws;
  bf16* WqT  = (bf16*)(ws + (16u << 20));
  bf16* WkvT = (bf16*)(ws + (16u << 20));
  bf16* kvb  = (bf16*)(ws + (32u << 20));
  float* cb  = (float*)(ws + (46u << 20));
  bf16* qb   = (bf16*)(ws + (48u << 20));
  bf16* attn = (bf16*)ws;
  bf16* WoT  = (bf16*)(ws + (16u << 20));

  // x -> bf16
  convert_kernel<<<(cT * cD) / (8 * 256), 256, 0, stream>>>(x, xb);
  // Wq^T bf16; q = xb * WqT^T (bf16 out)
  convT_kernel<<<dim3(cD / 64, cD / 64), 256, 0, stream>>>(Wq, WqT, cD, cD);
  gemm_bt_kernel<128, bf16><<<dim3(cD / 128, cT / 128), 256, 0, stream>>>(
      xb, WqT, qb, cT, cD, cD);
  // Wk^T|Wv^T bf16 (fused 2048x4096); kv = xb * WkvT^T (bf16 out)
  convT_kernel<<<dim3((cKV * cHD) / 64, cD / 64), 256, 0, stream>>>(Wk, WkvT, cD, cKV * cHD);
  convT_kernel<<<dim3((cKV * cHD) / 64, cD / 64), 256, 0, stream>>>(
      Wv, WkvT + (size_t)(cKV * cHD) * cD, cD, cKV * cHD);
  gemm_bt_kernel<64, bf16><<<dim3((2 * cKV * cHD) / 64, cT / 128), 256, 0, stream>>>(
      xb, WkvT, kvb, cT, 2 * cKV * cHD, cD);
  // rmsnorm + rope (in place, bf16); softmax shift bound
  norm_rope_kernel<<<(cT * (cH + cKV)) / 4, 256, 0, stream>>>(qb, kvb, qw, kw);
  bound_kernel<<<1, 64, 0, stream>>>(qw, kw, cb);
  // flash attention -> attn bf16 (reuses xb region)
  flash_kernel<<<dim3(cT / 128, cH), 256, 0, stream>>>(qb, kvb, cb, attn);
  // Wo^T bf16 (overwrites WkvT/kv region - both dead); out = attn * WoT^T (fp32)
  convT_kernel<<<dim3(cD / 64, cD / 64), 256, 0, stream>>>(Wo, WoT, cD, cD);
  gemm_bt_kernel<128, float><<<dim3(cD / 128, cT / 128), 256, 0, stream>>>(
      attn, WoT, out, cT, cD, cD);
}